// Round 7
// baseline (3856.745 us; speedup 1.0000x reference)
//
#include <hip/hip_runtime.h>
#include <hip/hip_bf16.h>

#define NL  3
#define NB  128
#define NT  256
#define NH  512
#define NH3 1536
#define NBH (NB*NH)      // 65536
#define NM  (NB*NT)      // 32768

typedef __bf16 bf16x8 __attribute__((ext_vector_type(8)));
typedef float  floatx4 __attribute__((ext_vector_type(4)));
typedef __hip_bfloat16 bf16;
typedef unsigned long long u64;

__device__ __forceinline__ floatx4 mfma16(bf16x8 a, bf16x8 b, floatx4 c) {
  return __builtin_amdgcn_mfma_f32_16x16x32_bf16(a, b, c, 0, 0, 0);
}
__device__ __forceinline__ void gload16(const void* g, void* l) {
  __builtin_amdgcn_global_load_lds(
      (const __attribute__((address_space(1))) unsigned int*)g,
      (__attribute__((address_space(3))) unsigned int*)l, 16, 0, 0);
}
__device__ __forceinline__ float fsig(float x)  { return 1.0f / (1.0f + __expf(-x)); }
__device__ __forceinline__ float ftanh(float x) { return 2.0f / (1.0f + __expf(-2.0f*x)) - 1.0f; }
__device__ __forceinline__ float b2f(unsigned short u) {
  unsigned v = (unsigned)u << 16; float f; __builtin_memcpy(&f, &v, 4); return f;
}
__device__ __forceinline__ unsigned short f2b(float f) {
  bf16 h = __float2bfloat16(f); unsigned short u; __builtin_memcpy(&u, &h, 2); return u;
}
__device__ __forceinline__ u64 ald(const u64* p) {
  return __hip_atomic_load(p, __ATOMIC_RELAXED, __HIP_MEMORY_SCOPE_AGENT);
}
__device__ __forceinline__ void ast(u64* p, u64 v) {
  __hip_atomic_store(p, v, __ATOMIC_RELAXED, __HIP_MEMORY_SCOPE_AGENT);
}
__device__ __forceinline__ unsigned aldc(const unsigned* p) {
  return __hip_atomic_load(p, __ATOMIC_RELAXED, __HIP_MEMORY_SCOPE_AGENT);
}
__device__ __forceinline__ void astc(unsigned* p, unsigned v) {
  __hip_atomic_store(p, v, __ATOMIC_RELAXED, __HIP_MEMORY_SCOPE_AGENT);
}

// ---------- transpose + cvt weights: fp32 [NL][NH][NH3] -> bf16 [NL][NH3][NH] ----------
__global__ void transpose_cvt_kernel(const float* __restrict__ in, bf16* __restrict__ out) {
  __shared__ float tile[32][33];
  int l = blockIdx.z;
  int n0 = blockIdx.x * 32, k0 = blockIdx.y * 32;
  const float* src = in + (size_t)l * NH * NH3;
  bf16* dst = out + (size_t)l * NH3 * NH;
  int tx = threadIdx.x, ty = threadIdx.y;    // 32 x 8
#pragma unroll
  for (int i = 0; i < 4; i++)
    tile[ty + 8*i][tx] = src[(size_t)(k0 + ty + 8*i) * NH3 + n0 + tx];
  __syncthreads();
#pragma unroll
  for (int i = 0; i < 4; i++)
    dst[(size_t)(n0 + ty + 8*i) * NH + k0 + tx] = __float2bfloat16(tile[tx][ty + 8*i]);
}

// ---------- elementwise fp32 -> bf16 (x input) ----------
__global__ void cvt_x_kernel(const float* __restrict__ in, bf16* __restrict__ out) {
  size_t i = (size_t)blockIdx.x * blockDim.x + threadIdx.x;
  float4 v = ((const float4*)in)[i];
  ushort4 pk;
  pk.x = f2b(v.x); pk.y = f2b(v.y); pk.z = f2b(v.z); pk.w = f2b(v.w);
  ((ushort4*)out)[i] = pk;
}

// ---------- xp GEMM (round-2 proven): C[m][n] = A[m]@Bt[n]^T + bias[n], bf16 out ----------
__global__ void __launch_bounds__(256, 2) gemm_xp_kernel(
    const bf16* __restrict__ A, const bf16* __restrict__ Bt,
    const float* __restrict__ bias, bf16* __restrict__ C, int a_mode)
{
  __shared__ char alds[16384];
  __shared__ char blds[16384];
  int tid = threadIdx.x;
  int lane = tid & 63, w = tid >> 6;
  int mblk = blockIdx.x, nblk = blockIdx.y;
  int wm = w >> 1, wn = w & 1;
  int klane = (lane >> 4) * 8;
  int r0 = 2*w*16 + (lane & 15);
  size_t arow0, arow1;
  if (a_mode == 0) {
    arow0 = ((size_t)r0 * NT + mblk) * NH;
    arow1 = ((size_t)(r0 + 16) * NT + mblk) * NH;
  } else {
    arow0 = (size_t)(mblk*128 + r0) * NH;
    arow1 = arow0 + (size_t)16 * NH;
  }
  size_t brow0 = (size_t)(nblk*128 + 2*w*16 + (lane & 15)) * NH;
  size_t brow1 = brow0 + (size_t)16 * NH;

  floatx4 acc[4][4];
#pragma unroll
  for (int i = 0; i < 4; i++)
#pragma unroll
    for (int j = 0; j < 4; j++) acc[i][j] = (floatx4){0.f, 0.f, 0.f, 0.f};

  for (int kk = 0; kk < 8; kk++) {
    int kb = kk*64 + klane;
#pragma unroll
    for (int kt = 0; kt < 2; kt++) {
      int kg = kb + kt*32;
      gload16(A  + arow0 + kg, alds + (kt*8 + 2*w    ) * 1024);
      gload16(A  + arow1 + kg, alds + (kt*8 + 2*w + 1) * 1024);
      gload16(Bt + brow0 + kg, blds + (kt*8 + 2*w    ) * 1024);
      gload16(Bt + brow1 + kg, blds + (kt*8 + 2*w + 1) * 1024);
    }
    __syncthreads();
#pragma unroll
    for (int kt = 0; kt < 2; kt++) {
      bf16x8 af[4], bfr[4];
#pragma unroll
      for (int i = 0; i < 4; i++) af[i]  = *(const bf16x8*)(alds + ((kt*8 + wm*4 + i)*64 + lane)*16);
#pragma unroll
      for (int j = 0; j < 4; j++) bfr[j] = *(const bf16x8*)(blds + ((kt*8 + wn*4 + j)*64 + lane)*16);
#pragma unroll
      for (int i = 0; i < 4; i++)
#pragma unroll
        for (int j = 0; j < 4; j++)
          acc[i][j] = mfma16(af[i], bfr[j], acc[i][j]);
    }
    __syncthreads();
  }
  int cl = lane & 15, rbase = (lane >> 4) * 4;
#pragma unroll
  for (int i = 0; i < 4; i++) {
    int gm = mblk*128 + wm*64 + i*16 + rbase;
#pragma unroll
    for (int j = 0; j < 4; j++) {
      int gn = nblk*128 + wn*64 + j*16 + cl;
      float bv = bias[gn];
#pragma unroll
      for (int r = 0; r < 4; r++)
        C[(size_t)(gm + r) * NH3 + gn] = __float2bfloat16(acc[i][j][r] + bv);
    }
  }
}

// =====================================================================================
// gru_scan: 32 blocks = 8 groups x 4 col-blocks, 512 thr (8 waves). Per-step sync chain
// minimized: per-block FLAG STORES (no shared-counter RMW serialization), all-wave
// parallel polling (3 lanes/wave watch the 3 sibling flags; waves self-release via
// __all — no single-lane detect + release barrier), own-h kept on-CU via LDS
// double-buffer (staging fetches only the 3 sibling ranges). Two barriers per step.
// WAR safety: own-h ds_write for step t+1 targets buf[(t+1)&1]; all waves passed
// BARRIER_D(t-1) (after their buf[(t-1)&1] MFMA reads) before any wave reaches that
// write — parity buffers make the write safe without a third barrier.
// =====================================================================================
__global__ void __launch_bounds__(512, 2) gru_scan_kernel(
    const bf16*  __restrict__ wuT,   // [NH3][NH] bf16 (this layer)
    const float* __restrict__ br,    // [NH3] recurrent bias
    const bf16*  __restrict__ xp,    // [NM][NH3] bf16, row = t*NB + b (bias folded)
    bf16*        __restrict__ seq,   // [NT+1][B][H] bf16; slot 256 on entry = prev layer h_255
    float*       __restrict__ hlast, // [B][H] fp32 carry handoff
    float*       __restrict__ out,   // layer2: d_out; else null
    unsigned*    __restrict__ flags, // [8 groups][4 siblings] x 16-word spacing
    unsigned fbase, int layer)
{
  __shared__ __align__(16) char h_raw[2][16384];  // parity-buffered B-frags
  __shared__ int deadflag;
  int tid = threadIdx.x, lane = tid & 63, w = tid >> 6;   // 8 waves
  int g = blockIdx.x >> 2, c = blockIdx.x & 3;
  int bb0 = g * 16;
  int r16 = lane & 15, h4 = lane >> 4;
  int srow = tid & 15, ssc = tid >> 4;                    // staging (row, chunk)
  if (tid == 0) deadflag = 0;

  // ---- hoist weight A-fragments (loop-invariant): 3 x 16 x bf16x8 ----
  bf16x8 wf[3][16];
  float  bv[3][4];
#pragma unroll
  for (int G = 0; G < 3; G++) {
    const bf16* wrow = wuT + ((size_t)(G*NH + c*128 + w*16 + r16)) * NH + h4*8;
#pragma unroll
    for (int kt = 0; kt < 16; kt++) wf[G][kt] = *(const bf16x8*)(wrow + kt*32);
#pragma unroll
    for (int q = 0; q < 4; q++) bv[G][q] = br[G*NH + c*128 + w*16 + h4*4 + q];
  }

  // ---- fp32 carry: lane owns (row r16, cols c*128 + w*16 + h4*4 .. +4) ----
  float hreg[4];
  if (layer == 0) {
    hreg[0] = hreg[1] = hreg[2] = hreg[3] = 0.0f;
  } else {
    const float* hsrc = hlast + (size_t)(bb0 + r16) * NH + c*128 + w*16 + h4*4;
    float4 v = *(const float4*)hsrc;          // prev kernel's output: plain load OK
    hreg[0] = v.x; hreg[1] = v.y; hreg[2] = v.z; hreg[3] = v.w;
  }

  // own-h ds_write target geometry (next-step fragment position of this lane's 4 cols)
  int sc_own = c*16 + w*2 + (h4 >> 1);
  int own_off = (((sc_own >> 2)*64) + (sc_own & 3)*16 + r16)*16 + (h4 & 1)*8;

  u64* seqU = (u64*)seq;
  const unsigned* myflags = flags + (g*4 + (lane & 3))*16;  // lane<4 polls sibling lane
  unsigned* myflag = flags + (g*4 + c)*16;

  for (int t = 0; t < NT; t++) {
    char* buf  = h_raw[t & 1];
    char* bufN = h_raw[(t + 1) & 1];

    // prefetch xp_t for this lane (plain loads; written by an earlier dispatch)
    const u64* xq = (const u64*)(xp + ((size_t)t*NB + bb0 + r16)*NH3 + c*128 + w*16 + h4*4);
    u64 xv0 = xq[0], xv1 = xq[128], xv2 = xq[256];

    if (t > 0) {
      // all-wave parallel poll: lanes 0..3 (minus own c) watch sibling flags
      bool need = (lane < 4) && (lane != c);
      unsigned tgt = fbase + (unsigned)t;
      long sp = 0;
      for (;;) {
        bool ok = !need || (aldc(myflags) >= tgt);
        if (__all(ok)) break;
        if (++sp > (1L << 20)) { if (need) deadflag = 1; break; }
      }
      // stage the 3 sibling ranges of h_{t-1} (skip own c: already ds_written last step)
      const u64* src = seqU + ((size_t)t*NBH + (size_t)(bb0 + srow)*NH) / 4;
#pragma unroll
      for (int d = 0; d < 2; d++) {
        int sc = ssc + d*32;
        if ((sc >> 4) != c) {
          u64 q0 = ald(src + sc*2), q1 = ald(src + sc*2 + 1);
          u64* dst = (u64*)(buf + (((sc >> 2)*64) + (sc & 3)*16 + srow)*16);
          dst[0] = q0; dst[1] = q1;
        }
      }
    } else if (layer == 0) {
      // t==0, layer 0: h0 = 0
#pragma unroll
      for (int d = 0; d < 2; d++) {
        int sc = ssc + d*32;
        u64* dst = (u64*)(buf + (((sc >> 2)*64) + (sc & 3)*16 + srow)*16);
        dst[0] = 0ull; dst[1] = 0ull;
      }
    } else {
      // t==0, layer>0: full stage from slot NT (prev layer h_255), incl. own c
      const u64* src = seqU + ((size_t)NT*NBH + (size_t)(bb0 + srow)*NH) / 4;
#pragma unroll
      for (int d = 0; d < 2; d++) {
        int sc = ssc + d*32;
        u64 q0 = ald(src + sc*2), q1 = ald(src + sc*2 + 1);
        u64* dst = (u64*)(buf + (((sc >> 2)*64) + (sc & 3)*16 + srow)*16);
        dst[0] = q0; dst[1] = q1;
      }
    }
    __syncthreads();                   // BARRIER_S: staging visible to all waves
    if (deadflag) return;

    // ---- rec^T = Wu_cols x h : 3 tiles/wave, K=512 ----
    floatx4 ac0 = (floatx4){0,0,0,0}, ac1 = (floatx4){0,0,0,0}, ac2 = (floatx4){0,0,0,0};
#pragma unroll
    for (int kt = 0; kt < 16; kt++) {
      bf16x8 hb = *(const bf16x8*)(buf + (kt*64 + lane)*16);
      ac0 = mfma16(wf[0][kt], hb, ac0);
      ac1 = mfma16(wf[1][kt], hb, ac1);
      ac2 = mfma16(wf[2][kt], hb, ac2);
    }

    // ---- gates in registers ----
    unsigned short pk[4];
#pragma unroll
    for (int q = 0; q < 4; q++) {
      float rz = ac0[q] + bv[0][q];
      float rr = ac1[q] + bv[1][q];
      float rh = ac2[q] + bv[2][q];
      float xz = b2f((unsigned short)(xv0 >> (16*q)));
      float xr = b2f((unsigned short)(xv1 >> (16*q)));
      float xh = b2f((unsigned short)(xv2 >> (16*q)));
      float z  = fsig(xz + rz);
      float r  = fsig(xr + rr);
      float hh = ftanh(xh + r * rh);
      float hn = z * hreg[q] + (1.0f - z) * hh;
      hreg[q] = hn;
      pk[q] = f2b(hn);
    }
    u64 pv; __builtin_memcpy(&pv, pk, 8);
    // publish h_t -> seq slot t+1 for siblings / next layer (device-coherent, early)
    ast(seqU + ((size_t)(t+1)*NBH + (size_t)(bb0 + r16)*NH)/4 + c*32 + w*4 + h4, pv);
    // own-h into next step's fragment buffer (LDS, parity-safe)
    *(u64*)(bufN + own_off) = pv;

    if (layer == 2) {                  // fp32 chain straight into d_out [B][T][H] flat
      float* o = out + ((size_t)(bb0 + r16)*NT + t)*NH + c*128 + w*16 + h4*4;
      *(float4*)o = (float4){hreg[0], hreg[1], hreg[2], hreg[3]};
      if (t == NT - 1) {
        float* o2 = out + (size_t)NM*NH + (size_t)(bb0 + r16)*NH + c*128 + w*16 + h4*4;
        *(float4*)o2 = (float4){hreg[0], hreg[1], hreg[2], hreg[3]};
      }
    } else if (t == NT - 1) {          // fp32 carry handoff for next layer
      float* o = hlast + (size_t)(bb0 + r16)*NH + c*128 + w*16 + h4*4;
      *(float4*)o = (float4){hreg[0], hreg[1], hreg[2], hreg[3]};
    }

    __syncthreads();                   // BARRIER_D: all waves' publishes acked (vmcnt 0)
    if (tid == 0 && t < NT - 1)
      astc(myflag, fbase + (unsigned)(t + 1));   // flag store — no RMW
  }
}

extern "C" void kernel_launch(void* const* d_in, const int* in_sizes, int n_in,
                              void* d_out, int out_size, void* d_ws, size_t ws_size,
                              hipStream_t stream) {
  const float* x   = (const float*)d_in[0];
  const float* wk  = (const float*)d_in[1];
  const float* wu  = (const float*)d_in[2];
  const float* bis = (const float*)d_in[3];
  float* out = (float*)d_out;

  // workspace layout:
  //   wkT   @ 0            4,718,592   [3][1536][512] bf16
  //   wuT   @ 4,718,592    4,718,592
  //   xp    @ 9,437,184  100,663,296   [32768][1536] bf16
  //   seq   @ 110,100,480 33,685,504   [257][128][512] bf16 (xb aliases base)
  //   hlast @ 143,785,984    262,144   [128][512] fp32
  //   flags @ 144,048,128      2,048   [8][4] x 64B spacing
  const size_t REQ = 144050176;
  if (ws_size < REQ) {
    hipMemsetAsync(d_out, 0, (size_t)out_size * 4, stream);
    return;
  }
  char* ws = (char*)d_ws;
  bf16*  wkT   = (bf16*)(ws);
  bf16*  wuT   = (bf16*)(ws + 4718592);
  bf16*  xp    = (bf16*)(ws + 9437184);
  bf16*  seq   = (bf16*)(ws + 110100480);
  bf16*  xb    = seq;                          // alias: dead after layer-0 GEMM
  float* hlast = (float*)(ws + 143785984);
  unsigned* flags = (unsigned*)(ws + 144048128);

  hipMemsetAsync(flags, 0, 2048, stream);
  transpose_cvt_kernel<<<dim3(48,16,3), dim3(32,8), 0, stream>>>(wk, wkT);
  transpose_cvt_kernel<<<dim3(48,16,3), dim3(32,8), 0, stream>>>(wu, wuT);
  cvt_x_kernel<<<(NM*NH/4)/256, 256, 0, stream>>>(x, xb);

  const size_t WS = (size_t)NH3 * NH;   // per-layer weight stride

  // layer 0
  gemm_xp_kernel<<<dim3(256,12), 256, 0, stream>>>(xb, wkT, bis + 0*2*NH3, xp, 0);
  gru_scan_kernel<<<32, 512, 0, stream>>>(wuT, bis + 0*2*NH3 + NH3, xp,
      seq, hlast, nullptr, flags, 0u, 0);
  // layer 1 (gemm reads seq slots 1..256 = layer-0 h)
  gemm_xp_kernel<<<dim3(256,12), 256, 0, stream>>>(seq + NBH, wkT + WS, bis + 1*2*NH3, xp, 1);
  gru_scan_kernel<<<32, 512, 0, stream>>>(wuT + WS, bis + 1*2*NH3 + NH3, xp,
      seq, hlast, nullptr, flags, 256u, 1);
  // layer 2 (fp32 chain straight into d_out)
  gemm_xp_kernel<<<dim3(256,12), 256, 0, stream>>>(seq + NBH, wkT + 2*WS, bis + 2*2*NH3, xp, 1);
  gru_scan_kernel<<<32, 512, 0, stream>>>(wuT + 2*WS, bis + 2*2*NH3 + NH3, xp,
      seq, hlast, out, flags, 512u, 2);

  (void)in_sizes; (void)n_in; (void)out_size; (void)ws_size;
}